// Round 11
// baseline (373.216 us; speedup 1.0000x reference)
//
#include <hip/hip_runtime.h>
#include <hip/hip_bf16.h>
#include <math.h>
#include <stdint.h>

#define NB 128     // batch (images and captions)
#define NR 36      // regions
#define NW 64      // words
#define ND 1024    // dim
#define MT 48      // NR padded to 3 MFMA m-tiles
#define EPSF 1e-8f
#define LAM_SM 9.0f
#define LAM_LSE 6.0f
#define MARGINF 0.2f

typedef _Float16 f16;
typedef f16 f16x4 __attribute__((ext_vector_type(4)));
typedef f16 f16x8 __attribute__((ext_vector_type(8)));
typedef float f32x4 __attribute__((ext_vector_type(4)));

__device__ __forceinline__ void gld_lds16(const void* g, void* l) {
    __builtin_amdgcn_global_load_lds(
        (const __attribute__((address_space(1))) uint32_t*)(uintptr_t)g,
        (__attribute__((address_space(3))) uint32_t*)(uint32_t)(uintptr_t)l,
        16, 0, 0);
}

// ------- kernel 0: fp32 -> f16 (+ pad) + ncap + per-image Gram, one launch -------
// grid (NB, 15): y<14 -> convert 8 rows each; y==14 -> Gram block (reads fp32 im).
__global__ __launch_bounds__(256) void prep_kernel(
    const float* __restrict__ im, const float* __restrict__ s,
    f16* __restrict__ im48, f16* __restrict__ s16, float* __restrict__ ncap,
    f16* __restrict__ Mg16) {
    __shared__ __align__(16) char Gs[8192];   // gram staging [64 rows][128 B]
    const int b = blockIdx.x, y = blockIdx.y, t = threadIdx.x;

    if (y < 14) {
        const int lr = t >> 5, g = t & 31;   // local row 0..7, lane-in-row 0..31
        const int row = y * 8 + lr;          // 0..111
        if (row < MT) {
            f16x4* dst = (f16x4*)(im48 + ((size_t)b * MT + row) * ND);
            if (row < NR) {
                const float4* src = (const float4*)(im + ((size_t)b * NR + row) * ND);
                #pragma unroll
                for (int e = 0; e < 8; ++e) {
                    float4 v = src[g + e * 32];
                    dst[g + e * 32] = (f16x4){(f16)v.x, (f16)v.y, (f16)v.z, (f16)v.w};
                }
            } else {
                #pragma unroll
                for (int e = 0; e < 8; ++e)
                    dst[g + e * 32] = (f16x4){(f16)0.f, (f16)0.f, (f16)0.f, (f16)0.f};
            }
        } else {
            const int w = row - MT;
            const float4* src = (const float4*)(s + ((size_t)b * NW + w) * ND);
            f16x4* dst = (f16x4*)(s16 + ((size_t)b * NW + w) * ND);
            float ss = 0.f;
            #pragma unroll
            for (int e = 0; e < 8; ++e) {
                float4 v = src[g + e * 32];
                dst[g + e * 32] = (f16x4){(f16)v.x, (f16)v.y, (f16)v.z, (f16)v.w};
                ss += v.x * v.x + v.y * v.y + v.z * v.z + v.w * v.w;
            }
            #pragma unroll
            for (int off = 1; off < 32; off <<= 1) ss += __shfl_xor(ss, off, 32);
            if (g == 0) ncap[b * NW + w] = sqrtf(ss);
        }
        return;
    }

    // ---- Gram block: Mg16[b] = G . G^T, G = f16(im[b]) zero-padded to 64 rows ----
    const int wave = t >> 6, lane = t & 63;
    const int quad = lane >> 4, l16 = lane & 15;
    const int nt = wave;                     // n-tile 0..3 (cols); cols >=36 end up 0
    f32x4 acc[3];
    acc[0] = (f32x4){0.f, 0.f, 0.f, 0.f};
    acc[1] = (f32x4){0.f, 0.f, 0.f, 0.f};
    acc[2] = (f32x4){0.f, 0.f, 0.f, 0.f};
    const float* imb = im + (size_t)b * NR * ND;

    for (int kk = 0; kk < ND; kk += 64) {
        for (int cidx = t; cidx < 512; cidx += 256) {
            int row = cidx >> 3, c = cidx & 7;
            f16x8 hv;
            if (row < NR) {
                const float4* sp = (const float4*)(imb + (size_t)row * ND + kk + c * 8);
                float4 v0 = sp[0], v1 = sp[1];
                hv = (f16x8){(f16)v0.x, (f16)v0.y, (f16)v0.z, (f16)v0.w,
                             (f16)v1.x, (f16)v1.y, (f16)v1.z, (f16)v1.w};
            } else {
                hv = (f16x8){(f16)0.f, (f16)0.f, (f16)0.f, (f16)0.f,
                             (f16)0.f, (f16)0.f, (f16)0.f, (f16)0.f};
            }
            *(f16x8*)(Gs + row * 128 + ((c ^ (row & 7)) * 16)) = hv;
        }
        __syncthreads();
        #pragma unroll
        for (int ks = 0; ks < 2; ++ks) {
            int brow = nt * 16 + l16;
            f16x8 bf = *(const f16x8*)(Gs + brow * 128 + (((ks * 4 + quad) ^ (brow & 7)) * 16));
            #pragma unroll
            for (int mt = 0; mt < 3; ++mt) {
                int arow = mt * 16 + l16;
                f16x8 af = *(const f16x8*)(Gs + arow * 128 + (((ks * 4 + quad) ^ (arow & 7)) * 16));
                acc[mt] = __builtin_amdgcn_mfma_f32_16x16x32_f16(af, bf, acc[mt], 0, 0, 0);
            }
        }
        __syncthreads();
    }
    f16* Mb = Mg16 + (size_t)b * (MT * NW);
    #pragma unroll
    for (int mt = 0; mt < 3; ++mt) {
        #pragma unroll
        for (int r = 0; r < 4; ++r) {
            int row = mt * 16 + quad * 4 + r;
            Mb[row * NW + nt * 16 + l16] = (f16)acc[mt][r];
        }
    }
}

// ---------------- kernel B: fused GEMM + epilogue, hybrid operand sourcing -----
// Block tile 96x128 = 2 images x 2 captions; wave = one pair (acc[3][4]).
// A fragments: direct global (L1/L2-hot: all gy-siblings share the 24KB slice).
// B: LDS-staged, BK=128 (32KB, 256B rows, 16-chunk XOR swizzle, 2-way max=free).
// Barriers halve vs R8 (8 iters); occupancy stays 5 blocks/CU.
__global__ __launch_bounds__(256) void fused_pair_kernel(
    const f16* __restrict__ im48, const f16* __restrict__ s16,
    const int* __restrict__ s_l, const f16* __restrict__ Mg16,
    const float* __restrict__ ncap, float* __restrict__ scores) {
    __shared__ __align__(16) char lds[32768];   // B staging [128 rows][256 B]
    char* Bs = lds;
    const int t = threadIdx.x;
    const int wave = t >> 6, lane = t & 63;
    const int quad = lane >> 4, l16 = lane & 15;
    const int wi = wave >> 1, wj = wave & 1;

    // gx fast: XCD (~lin%8) sees gx = x, x+8, ... -> B slice (16 captions) L2-hot;
    // gy slow: all XCDs sweep the same A window concurrently (L2/L3-hot).
    const int lin = blockIdx.x;            // 0..4095
    const int gx = lin & 63, gy = lin >> 6;
    const int i = gy * 2 + wi;             // this wave's image
    const int j = gx * 2 + wj;             // this wave's caption
    const int L = s_l[j];

    const f16* Ai = im48 + (size_t)i * (MT * ND);        // this wave's image rows
    const f16* Bb = s16 + (size_t)gx * 2 * (NW * ND);    // 128 contiguous rows

    // B staging: 8 issues of 16B per thread per k128 iter
    int boff[8];
    #pragma unroll
    for (int q = 0; q < 8; ++q) {
        int f = q * 4096 + t * 16;
        int row = f >> 8, c = (f >> 4) & 15;
        boff[q] = row * ND + ((c ^ (row & 15)) * 8);
    }

    f32x4 acc[3][4];
    #pragma unroll
    for (int mi = 0; mi < 3; ++mi)
        #pragma unroll
        for (int nt = 0; nt < 4; ++nt)
            acc[mi][nt] = (f32x4){0.f, 0.f, 0.f, 0.f};

    for (int kk = 0; kk < ND; kk += 128) {
        #pragma unroll
        for (int q = 0; q < 8; ++q)
            gld_lds16(Bb + boff[q] + kk, lds + q * 4096 + t * 16);
        __syncthreads();
        #pragma unroll
        for (int ks = 0; ks < 4; ++ks) {
            f16x8 af[3], bf[4];
            #pragma unroll
            for (int mi = 0; mi < 3; ++mi)
                af[mi] = *(const f16x8*)(Ai + (mi * 16 + l16) * ND + kk + ks * 32 + quad * 8);
            #pragma unroll
            for (int nt = 0; nt < 4; ++nt) {
                int row = wj * 64 + nt * 16 + l16;
                int pc = (ks * 4 + quad) ^ (row & 15);
                bf[nt] = *(const f16x8*)(Bs + row * 256 + pc * 16);
            }
            #pragma unroll
            for (int mi = 0; mi < 3; ++mi)
                #pragma unroll
                for (int nt = 0; nt < 4; ++nt)
                    acc[mi][nt] = __builtin_amdgcn_mfma_f32_16x16x32_f16(af[mi], bf[nt], acc[mi][nt], 0, 0, 0);
        }
        __syncthreads();
    }

    // ---- wave-private epilogue (verified R3..R10 math) ----
    char* waveE = lds + wave * 8192;   // staging LDS dead after final barrier
    {   // zero E^T rows 48..63 (chunks 6,7): pad/poison guard for quadform
        int col = lane;
        f16x8 z = {(f16)0.f,(f16)0.f,(f16)0.f,(f16)0.f,(f16)0.f,(f16)0.f,(f16)0.f,(f16)0.f};
        *(f16x8*)(waveE + col * 128 + ((6 ^ (col & 7)) * 16)) = z;
        *(f16x8*)(waveE + col * 128 + ((7 ^ (col & 7)) * 16)) = z;
    }

    // -- per-row l2-norm reciprocal (rows >= 36 -> 0) --
    float rn[3][4];
    #pragma unroll
    for (int mi = 0; mi < 3; ++mi) {
        #pragma unroll
        for (int r = 0; r < 4; ++r) {
            int row = mi * 16 + quad * 4 + r;
            float ss = 0.f;
            #pragma unroll
            for (int nt = 0; nt < 4; ++nt) {
                int col = nt * 16 + l16;
                float v = acc[mi][nt][r];
                float lv = v > 0.f ? v : 0.1f * v;
                if (col < L) ss += lv * lv;
            }
            ss += __shfl_xor(ss, 1, 64);
            ss += __shfl_xor(ss, 2, 64);
            ss += __shfl_xor(ss, 4, 64);
            ss += __shfl_xor(ss, 8, 64);
            rn[mi][r] = (row < NR) ? 1.0f / (sqrtf(ss) + EPSF) : 0.f;
        }
    }
    // -- e = exp(9*an): write E^T f16 (swizzled); cs/nu per-col partials --
    float cs[4] = {0.f, 0.f, 0.f, 0.f}, nu[4] = {0.f, 0.f, 0.f, 0.f};
    #pragma unroll
    for (int mi = 0; mi < 3; ++mi) {
        #pragma unroll
        for (int nt = 0; nt < 4; ++nt) {
            int col = nt * 16 + l16;
            f16x4 ew;
            #pragma unroll
            for (int r = 0; r < 4; ++r) {
                float v = acc[mi][nt][r];
                float lv = v > 0.f ? v : 0.1f * v;
                float e = __expf(LAM_SM * ((col < L) ? lv * rn[mi][r] : 0.f));
                ew[r] = (f16)e;
                if (mi * 16 + quad * 4 + r < NR) { cs[nt] += e; nu[nt] += e * v; }
            }
            int c = mi * 2 + (quad >> 1);
            *(f16x4*)(waveE + col * 128 + ((c ^ (col & 7)) * 16) + (quad & 1) * 8) = ew;
        }
    }
    #pragma unroll
    for (int nt = 0; nt < 4; ++nt) {
        cs[nt] += __shfl_xor(cs[nt], 16, 64); cs[nt] += __shfl_xor(cs[nt], 32, 64);
        nu[nt] += __shfl_xor(nu[nt], 16, 64); nu[nt] += __shfl_xor(nu[nt], 32, 64);
    }
    // acc dead here -> pressure drops before quadform.

    // -- quadform mi-at-a-time: y = M[mi,:] x E^T; qf += e . y --
    const f16* Mi = Mg16 + (size_t)i * (MT * NW);
    float qf[4] = {0.f, 0.f, 0.f, 0.f};
    #pragma unroll
    for (int mi = 0; mi < 3; ++mi) {
        f32x4 y[4];
        #pragma unroll
        for (int nt = 0; nt < 4; ++nt) y[nt] = (f32x4){0.f, 0.f, 0.f, 0.f};
        #pragma unroll
        for (int ks = 0; ks < 2; ++ks) {
            f16x8 aq = *(const f16x8*)(Mi + (mi * 16 + l16) * NW + ks * 32 + quad * 8);
            #pragma unroll
            for (int nt = 0; nt < 4; ++nt) {
                int col = nt * 16 + l16;
                int pch = (ks * 4 + quad) ^ (col & 7);
                f16x8 bq = *(const f16x8*)(waveE + col * 128 + pch * 16);
                y[nt] = __builtin_amdgcn_mfma_f32_16x16x32_f16(aq, bq, y[nt], 0, 0, 0);
            }
        }
        int row0 = mi * 16 + quad * 4;
        int c = row0 >> 3, sub = (row0 >> 2) & 1;
        #pragma unroll
        for (int nt = 0; nt < 4; ++nt) {
            int col = nt * 16 + l16;
            f16x4 ev = *(const f16x4*)(waveE + col * 128 + ((c ^ (col & 7)) * 16) + sub * 8);
            #pragma unroll
            for (int r = 0; r < 4; ++r) qf[nt] += y[nt][r] * (float)ev[r];
        }
    }
    #pragma unroll
    for (int nt = 0; nt < 4; ++nt) {
        qf[nt] += __shfl_xor(qf[nt], 16, 64); qf[nt] += __shfl_xor(qf[nt], 32, 64);
    }
    // -- finalize: cosine row values, LSE over words, write score --
    float lse = 0.f;
    #pragma unroll
    for (int nt = 0; nt < 4; ++nt) {
        int col = nt * 16 + l16;
        float num  = nu[nt] / cs[nt];
        float nwei = sqrtf(fmaxf(qf[nt], 0.f)) / cs[nt];
        float nc   = ncap[j * NW + col];
        float rowv = num / fmaxf(nc * nwei, EPSF);
        lse += (col < L) ? __expf(LAM_LSE * rowv) : 0.f;
    }
    lse += __shfl_xor(lse, 1, 64);
    lse += __shfl_xor(lse, 2, 64);
    lse += __shfl_xor(lse, 4, 64);
    lse += __shfl_xor(lse, 8, 64);
    if (lane == 0) scores[i * NB + j] = __logf(lse) / LAM_LSE;
}

// ---------------- kernel C: contrastive loss reduction (LDS-staged S) ------------
__global__ __launch_bounds__(256) void loss_kernel(const float* __restrict__ S,
                                                   float* __restrict__ out) {
    __shared__ __align__(16) float Sl[NB * NB];
    __shared__ float part[NB];
    __shared__ float wsum[2];
    int t = threadIdx.x;
    for (int c = t; c < (NB * NB) / 4; c += 256)
        ((float4*)Sl)[c] = ((const float4*)S)[c];
    __syncthreads();
    if (t < NB) {
        float dii = Sl[t * NB + t];
        float rmax = 0.f, cmax = 0.f;
        for (int k = 0; k < NB; ++k) {
            if (k != t) {
                float vs = MARGINF + Sl[t * NB + k] - dii;
                rmax = fmaxf(rmax, fmaxf(vs, 0.f));
                float vi = MARGINF + Sl[k * NB + t] - dii;
                cmax = fmaxf(cmax, fmaxf(vi, 0.f));
            }
        }
        part[t] = rmax + cmax;
    }
    __syncthreads();
    if (t < NB) {
        float v = part[t];
        #pragma unroll
        for (int off = 1; off < 64; off <<= 1) v += __shfl_xor(v, off, 64);
        if ((t & 63) == 0) wsum[t >> 6] = v;
    }
    __syncthreads();
    if (t == 0) out[0] = wsum[0] + wsum[1];
}

extern "C" void kernel_launch(void* const* d_in, const int* in_sizes, int n_in,
                              void* d_out, int out_size, void* d_ws, size_t ws_size,
                              hipStream_t stream) {
    const float* im  = (const float*)d_in[0];
    const float* s   = (const float*)d_in[1];
    const int*   s_l = (const int*)d_in[2];

    float* scores = (float*)d_ws;                          // 16384 f32
    float* ncap   = scores + NB * NB;                      // 8192 f32
    f16*   Mg16   = (f16*)(ncap + NB * NW);                // 128*48*64
    f16*   im48   = Mg16 + (size_t)NB * MT * NW;           // 128*48*1024
    f16*   s16    = im48 + (size_t)NB * MT * ND;           // 128*64*1024

    dim3 pgrid(NB, 15);
    prep_kernel<<<pgrid, 256, 0, stream>>>(im, s, im48, s16, ncap, Mg16);
    fused_pair_kernel<<<4096, 256, 0, stream>>>(im48, s16, s_l, Mg16, ncap, scores);
    loss_kernel<<<1, 256, 0, stream>>>(scores, (float*)d_out);
}

// Round 12
// 240.281 us; speedup vs baseline: 1.5532x; 1.5532x over previous
//
#include <hip/hip_runtime.h>
#include <hip/hip_bf16.h>
#include <math.h>
#include <stdint.h>

#define NB 128     // batch (images and captions)
#define NR 36      // regions
#define NW 64      // words
#define ND 1024    // dim
#define MT 48      // NR padded to 3 MFMA m-tiles
#define EPSF 1e-8f
#define LAM_SM 9.0f
#define LAM_LSE 6.0f
#define MARGINF 0.2f

typedef _Float16 f16;
typedef f16 f16x4 __attribute__((ext_vector_type(4)));
typedef f16 f16x8 __attribute__((ext_vector_type(8)));
typedef float f32x4 __attribute__((ext_vector_type(4)));

__device__ __forceinline__ void gld_lds16(const void* g, void* l) {
    __builtin_amdgcn_global_load_lds(
        (const __attribute__((address_space(1))) uint32_t*)(uintptr_t)g,
        (__attribute__((address_space(3))) uint32_t*)(uint32_t)(uintptr_t)l,
        16, 0, 0);
}

// pack 4 floats -> 4 fp8 e4m3 (OCP, HW RNE+satfinite) in one uint32
__device__ __forceinline__ uint32_t pk_fp8x4(float4 v) {
    uint32_t w = 0;
    w = __builtin_amdgcn_cvt_pk_fp8_f32(v.x, v.y, w, false);  // bytes 0,1
    w = __builtin_amdgcn_cvt_pk_fp8_f32(v.z, v.w, w, true);   // bytes 2,3
    return w;
}

// ------- kernel 0: fp32 -> fp8 (+ pad) + ncap + per-image f16 Gram, one launch ----
// grid (NB, 15): y<14 -> convert 8 rows each; y==14 -> Gram block (reads fp32 im).
__global__ __launch_bounds__(256) void prep_kernel(
    const float* __restrict__ im, const float* __restrict__ s,
    uint8_t* __restrict__ im8, uint8_t* __restrict__ s8, float* __restrict__ ncap,
    f16* __restrict__ Mg16) {
    __shared__ __align__(16) char Gs[8192];   // gram staging [64 rows][128 B]
    const int b = blockIdx.x, y = blockIdx.y, t = threadIdx.x;

    if (y < 14) {
        const int lr = t >> 5, g = t & 31;   // local row 0..7, lane-in-row 0..31
        const int row = y * 8 + lr;          // 0..111
        if (row < MT) {
            uint32_t* dst = (uint32_t*)(im8 + ((size_t)b * MT + row) * ND);
            if (row < NR) {
                const float4* src = (const float4*)(im + ((size_t)b * NR + row) * ND);
                #pragma unroll
                for (int e = 0; e < 8; ++e)
                    dst[g + e * 32] = pk_fp8x4(src[g + e * 32]);
            } else {
                #pragma unroll
                for (int e = 0; e < 8; ++e) dst[g + e * 32] = 0u;
            }
        } else {
            const int w = row - MT;
            const float4* src = (const float4*)(s + ((size_t)b * NW + w) * ND);
            uint32_t* dst = (uint32_t*)(s8 + ((size_t)b * NW + w) * ND);
            float ss = 0.f;
            #pragma unroll
            for (int e = 0; e < 8; ++e) {
                float4 v = src[g + e * 32];
                dst[g + e * 32] = pk_fp8x4(v);
                ss += v.x * v.x + v.y * v.y + v.z * v.z + v.w * v.w;
            }
            #pragma unroll
            for (int off = 1; off < 32; off <<= 1) ss += __shfl_xor(ss, off, 32);
            if (g == 0) ncap[b * NW + w] = sqrtf(ss);
        }
        return;
    }

    // ---- Gram block: Mg16[b] = G . G^T, G = f16(im[b]) zero-padded to 64 rows ----
    const int wave = t >> 6, lane = t & 63;
    const int quad = lane >> 4, l16 = lane & 15;
    const int nt = wave;                     // n-tile 0..3 (cols); cols >=36 end up 0
    f32x4 acc[3];
    acc[0] = (f32x4){0.f, 0.f, 0.f, 0.f};
    acc[1] = (f32x4){0.f, 0.f, 0.f, 0.f};
    acc[2] = (f32x4){0.f, 0.f, 0.f, 0.f};
    const float* imb = im + (size_t)b * NR * ND;

    for (int kk = 0; kk < ND; kk += 64) {
        for (int cidx = t; cidx < 512; cidx += 256) {
            int row = cidx >> 3, c = cidx & 7;
            f16x8 hv;
            if (row < NR) {
                const float4* sp = (const float4*)(imb + (size_t)row * ND + kk + c * 8);
                float4 v0 = sp[0], v1 = sp[1];
                hv = (f16x8){(f16)v0.x, (f16)v0.y, (f16)v0.z, (f16)v0.w,
                             (f16)v1.x, (f16)v1.y, (f16)v1.z, (f16)v1.w};
            } else {
                hv = (f16x8){(f16)0.f, (f16)0.f, (f16)0.f, (f16)0.f,
                             (f16)0.f, (f16)0.f, (f16)0.f, (f16)0.f};
            }
            *(f16x8*)(Gs + row * 128 + ((c ^ (row & 7)) * 16)) = hv;
        }
        __syncthreads();
        #pragma unroll
        for (int ks = 0; ks < 2; ++ks) {
            int brow = nt * 16 + l16;
            f16x8 bf = *(const f16x8*)(Gs + brow * 128 + (((ks * 4 + quad) ^ (brow & 7)) * 16));
            #pragma unroll
            for (int mt = 0; mt < 3; ++mt) {
                int arow = mt * 16 + l16;
                f16x8 af = *(const f16x8*)(Gs + arow * 128 + (((ks * 4 + quad) ^ (arow & 7)) * 16));
                acc[mt] = __builtin_amdgcn_mfma_f32_16x16x32_f16(af, bf, acc[mt], 0, 0, 0);
            }
        }
        __syncthreads();
    }
    f16* Mb = Mg16 + (size_t)b * (MT * NW);
    #pragma unroll
    for (int mt = 0; mt < 3; ++mt) {
        #pragma unroll
        for (int r = 0; r < 4; ++r) {
            int row = mt * 16 + quad * 4 + r;
            Mb[row * NW + nt * 16 + l16] = (f16)acc[mt][r];
        }
    }
}

// ---------------- kernel B: fused GEMM + epilogue, fp8 operands ----------------
// Block tile 96x128 = 2 images x 2 captions; wave = one pair (acc[3][4]).
// fp8 e4m3 staging: BK=128 -> rows 128 B, exact XOR swizzle; A 12KB + B 16KB =
// 28KB < 32KB -> 5 blocks/CU; barriers halve vs R8 (8 iters). Fragments 8B/lane.
// Epilogue (f32 acc -> f16 E / f16 Gram quadform) identical to R8/R10 verified.
#define A_LDS 12288   // 96 rows x 128 B
__global__ __launch_bounds__(256) void fused_pair_kernel(
    const uint8_t* __restrict__ im8, const uint8_t* __restrict__ s8,
    const int* __restrict__ s_l, const f16* __restrict__ Mg16,
    const float* __restrict__ ncap, float* __restrict__ scores) {
    __shared__ __align__(16) char lds[32768];   // staging 28KB; eT overlay 32KB
    const int t = threadIdx.x;
    const int wave = t >> 6, lane = t & 63;
    const int quad = lane >> 4, l16 = lane & 15;
    const int wi = wave >> 1, wj = wave & 1;

    // gx fast: XCD (~lin%8) sees gx = x, x+8, ... -> B slice (16 captions) L2-hot;
    // gy slow: all XCDs sweep the same A window concurrently (L2/L3-hot).
    const int lin = blockIdx.x;            // 0..4095
    const int gx = lin & 63, gy = lin >> 6;
    const int i = gy * 2 + wi;             // this wave's image
    const int j = gx * 2 + wj;             // this wave's caption
    const int L = s_l[j];

    const uint8_t* Ab = im8 + (size_t)gy * 2 * (MT * ND);   // 96 contiguous rows
    const uint8_t* Bb = s8 + (size_t)gx * 2 * (NW * ND);    // 128 contiguous rows

    // staging: 7 issues of 16B/thread per k128 iter (A q=0..2, B q=3..6)
    int goff[7];
    bool gact[7];
    const uint8_t* gbase[7];
    #pragma unroll
    for (int q = 0; q < 7; ++q) {
        int f = q * 4096 + t * 16;
        if (f < A_LDS) {
            int row = f >> 7, c = (f >> 4) & 7;
            goff[q] = row * ND + (c ^ (row & 7)) * 16;
            gact[q] = (row % MT) < NR;     // pad rows stay zero
            gbase[q] = Ab;
        } else {
            int f2 = f - A_LDS;
            int row = f2 >> 7, c = (f2 >> 4) & 7;
            goff[q] = row * ND + (c ^ (row & 7)) * 16;
            gact[q] = true;
            gbase[q] = Bb;
        }
    }

    // pre-zero the 24 pad rows of As (never DMA'd)
    if (t < 192) {
        int r = (t < 96) ? (36 + (t >> 3)) : (84 + ((t - 96) >> 3));
        *(float4*)(lds + r * 128 + (t & 7) * 16) = make_float4(0.f, 0.f, 0.f, 0.f);
    }

    f32x4 acc[3][4];
    #pragma unroll
    for (int mi = 0; mi < 3; ++mi)
        #pragma unroll
        for (int nt = 0; nt < 4; ++nt)
            acc[mi][nt] = (f32x4){0.f, 0.f, 0.f, 0.f};

    for (int kk = 0; kk < ND; kk += 128) {
        #pragma unroll
        for (int q = 0; q < 7; ++q)
            if (gact[q]) gld_lds16(gbase[q] + goff[q] + kk, lds + q * 4096 + t * 16);
        __syncthreads();
        #pragma unroll
        for (int ks = 0; ks < 4; ++ks) {
            const int c16 = ks * 2 + (quad >> 1);
            const int sub = (quad & 1) * 8;
            long af[3], bf[4];
            #pragma unroll
            for (int mi = 0; mi < 3; ++mi) {
                int row = wi * 48 + mi * 16 + l16;
                af[mi] = *(const long*)(lds + row * 128 + ((c16 ^ (row & 7)) * 16) + sub);
            }
            #pragma unroll
            for (int nt = 0; nt < 4; ++nt) {
                int row = wj * 64 + nt * 16 + l16;
                bf[nt] = *(const long*)(lds + A_LDS + row * 128 + ((c16 ^ (row & 7)) * 16) + sub);
            }
            #pragma unroll
            for (int mi = 0; mi < 3; ++mi)
                #pragma unroll
                for (int nt = 0; nt < 4; ++nt)
                    acc[mi][nt] = __builtin_amdgcn_mfma_f32_16x16x32_fp8_fp8(af[mi], bf[nt], acc[mi][nt], 0, 0, 0);
        }
        __syncthreads();
    }

    // ---- wave-private epilogue (verified R3..R10 math) ----
    char* waveE = lds + wave * 8192;   // staging LDS dead after final barrier
    {   // zero E^T rows 48..63 (chunks 6,7): pad/poison guard for quadform
        int col = lane;
        f16x8 z = {(f16)0.f,(f16)0.f,(f16)0.f,(f16)0.f,(f16)0.f,(f16)0.f,(f16)0.f,(f16)0.f};
        *(f16x8*)(waveE + col * 128 + ((6 ^ (col & 7)) * 16)) = z;
        *(f16x8*)(waveE + col * 128 + ((7 ^ (col & 7)) * 16)) = z;
    }

    // -- per-row l2-norm reciprocal (rows >= 36 -> 0) --
    float rn[3][4];
    #pragma unroll
    for (int mi = 0; mi < 3; ++mi) {
        #pragma unroll
        for (int r = 0; r < 4; ++r) {
            int row = mi * 16 + quad * 4 + r;
            float ss = 0.f;
            #pragma unroll
            for (int nt = 0; nt < 4; ++nt) {
                int col = nt * 16 + l16;
                float v = acc[mi][nt][r];
                float lv = v > 0.f ? v : 0.1f * v;
                if (col < L) ss += lv * lv;
            }
            ss += __shfl_xor(ss, 1, 64);
            ss += __shfl_xor(ss, 2, 64);
            ss += __shfl_xor(ss, 4, 64);
            ss += __shfl_xor(ss, 8, 64);
            rn[mi][r] = (row < NR) ? 1.0f / (sqrtf(ss) + EPSF) : 0.f;
        }
    }
    // -- e = exp(9*an): write E^T f16 (swizzled); cs/nu per-col partials --
    float cs[4] = {0.f, 0.f, 0.f, 0.f}, nu[4] = {0.f, 0.f, 0.f, 0.f};
    #pragma unroll
    for (int mi = 0; mi < 3; ++mi) {
        #pragma unroll
        for (int nt = 0; nt < 4; ++nt) {
            int col = nt * 16 + l16;
            f16x4 ew;
            #pragma unroll
            for (int r = 0; r < 4; ++r) {
                float v = acc[mi][nt][r];
                float lv = v > 0.f ? v : 0.1f * v;
                float e = __expf(LAM_SM * ((col < L) ? lv * rn[mi][r] : 0.f));
                ew[r] = (f16)e;
                if (mi * 16 + quad * 4 + r < NR) { cs[nt] += e; nu[nt] += e * v; }
            }
            int c = mi * 2 + (quad >> 1);
            *(f16x4*)(waveE + col * 128 + ((c ^ (col & 7)) * 16) + (quad & 1) * 8) = ew;
        }
    }
    #pragma unroll
    for (int nt = 0; nt < 4; ++nt) {
        cs[nt] += __shfl_xor(cs[nt], 16, 64); cs[nt] += __shfl_xor(cs[nt], 32, 64);
        nu[nt] += __shfl_xor(nu[nt], 16, 64); nu[nt] += __shfl_xor(nu[nt], 32, 64);
    }
    // acc dead here -> pressure drops before quadform.

    // -- quadform mi-at-a-time: y = M[mi,:] x E^T; qf += e . y --
    const f16* Mi = Mg16 + (size_t)i * (MT * NW);
    float qf[4] = {0.f, 0.f, 0.f, 0.f};
    #pragma unroll
    for (int mi = 0; mi < 3; ++mi) {
        f32x4 y[4];
        #pragma unroll
        for (int nt = 0; nt < 4; ++nt) y[nt] = (f32x4){0.f, 0.f, 0.f, 0.f};
        #pragma unroll
        for (int ks = 0; ks < 2; ++ks) {
            f16x8 aq = *(const f16x8*)(Mi + (mi * 16 + l16) * NW + ks * 32 + quad * 8);
            #pragma unroll
            for (int nt = 0; nt < 4; ++nt) {
                int col = nt * 16 + l16;
                int pch = (ks * 4 + quad) ^ (col & 7);
                f16x8 bq = *(const f16x8*)(waveE + col * 128 + pch * 16);
                y[nt] = __builtin_amdgcn_mfma_f32_16x16x32_f16(aq, bq, y[nt], 0, 0, 0);
            }
        }
        int row0 = mi * 16 + quad * 4;
        int c = row0 >> 3, sub = (row0 >> 2) & 1;
        #pragma unroll
        for (int nt = 0; nt < 4; ++nt) {
            int col = nt * 16 + l16;
            f16x4 ev = *(const f16x4*)(waveE + col * 128 + ((c ^ (col & 7)) * 16) + sub * 8);
            #pragma unroll
            for (int r = 0; r < 4; ++r) qf[nt] += y[nt][r] * (float)ev[r];
        }
    }
    #pragma unroll
    for (int nt = 0; nt < 4; ++nt) {
        qf[nt] += __shfl_xor(qf[nt], 16, 64); qf[nt] += __shfl_xor(qf[nt], 32, 64);
    }
    // -- finalize: cosine row values, LSE over words, write score --
    float lse = 0.f;
    #pragma unroll
    for (int nt = 0; nt < 4; ++nt) {
        int col = nt * 16 + l16;
        float num  = nu[nt] / cs[nt];
        float nwei = sqrtf(fmaxf(qf[nt], 0.f)) / cs[nt];
        float nc   = ncap[j * NW + col];
        float rowv = num / fmaxf(nc * nwei, EPSF);
        lse += (col < L) ? __expf(LAM_LSE * rowv) : 0.f;
    }
    lse += __shfl_xor(lse, 1, 64);
    lse += __shfl_xor(lse, 2, 64);
    lse += __shfl_xor(lse, 4, 64);
    lse += __shfl_xor(lse, 8, 64);
    if (lane == 0) scores[i * NB + j] = __logf(lse) / LAM_LSE;
}

// ---------------- kernel C: contrastive loss reduction (LDS-staged S) ------------
__global__ __launch_bounds__(256) void loss_kernel(const float* __restrict__ S,
                                                   float* __restrict__ out) {
    __shared__ __align__(16) float Sl[NB * NB];
    __shared__ float part[NB];
    __shared__ float wsum[2];
    int t = threadIdx.x;
    for (int c = t; c < (NB * NB) / 4; c += 256)
        ((float4*)Sl)[c] = ((const float4*)S)[c];
    __syncthreads();
    if (t < NB) {
        float dii = Sl[t * NB + t];
        float rmax = 0.f, cmax = 0.f;
        for (int k = 0; k < NB; ++k) {
            if (k != t) {
                float vs = MARGINF + Sl[t * NB + k] - dii;
                rmax = fmaxf(rmax, fmaxf(vs, 0.f));
                float vi = MARGINF + Sl[k * NB + t] - dii;
                cmax = fmaxf(cmax, fmaxf(vi, 0.f));
            }
        }
        part[t] = rmax + cmax;
    }
    __syncthreads();
    if (t < NB) {
        float v = part[t];
        #pragma unroll
        for (int off = 1; off < 64; off <<= 1) v += __shfl_xor(v, off, 64);
        if ((t & 63) == 0) wsum[t >> 6] = v;
    }
    __syncthreads();
    if (t == 0) out[0] = wsum[0] + wsum[1];
}

extern "C" void kernel_launch(void* const* d_in, const int* in_sizes, int n_in,
                              void* d_out, int out_size, void* d_ws, size_t ws_size,
                              hipStream_t stream) {
    const float* im  = (const float*)d_in[0];
    const float* s   = (const float*)d_in[1];
    const int*   s_l = (const int*)d_in[2];

    float*   scores = (float*)d_ws;                        // 16384 f32
    float*   ncap   = scores + NB * NB;                    // 8192 f32
    f16*     Mg16   = (f16*)(ncap + NB * NW);              // 128*48*64 f16
    uint8_t* im8    = (uint8_t*)(Mg16 + (size_t)NB * MT * NW);  // 128*48*1024 fp8
    uint8_t* s8     = im8 + (size_t)NB * MT * ND;          // 128*64*1024 fp8

    dim3 pgrid(NB, 15);
    prep_kernel<<<pgrid, 256, 0, stream>>>(im, s, im8, s8, ncap, Mg16);
    fused_pair_kernel<<<4096, 256, 0, stream>>>(im8, s8, s_l, Mg16, ncap, scores);
    loss_kernel<<<1, 256, 0, stream>>>(scores, (float*)d_out);
}

// Round 13
// 228.283 us; speedup vs baseline: 1.6349x; 1.0526x over previous
//
#include <hip/hip_runtime.h>
#include <hip/hip_bf16.h>
#include <math.h>
#include <stdint.h>

#define NB 128     // batch (images and captions)
#define NR 36      // regions
#define NW 64      // words
#define ND 1024    // dim
#define MT 48      // NR padded to 3 MFMA m-tiles
#define EPSF 1e-8f
#define LAM_SM 9.0f
#define LAM_LSE 6.0f
#define MARGINF 0.2f

typedef _Float16 f16;
typedef f16 f16x4 __attribute__((ext_vector_type(4)));
typedef f16 f16x8 __attribute__((ext_vector_type(8)));
typedef float f32x4 __attribute__((ext_vector_type(4)));
typedef int i32x4 __attribute__((ext_vector_type(4)));
typedef int i32x8 __attribute__((ext_vector_type(8)));

__device__ __forceinline__ void gld_lds16(const void* g, void* l) {
    __builtin_amdgcn_global_load_lds(
        (const __attribute__((address_space(1))) uint32_t*)(uintptr_t)g,
        (__attribute__((address_space(3))) uint32_t*)(uint32_t)(uintptr_t)l,
        16, 0, 0);
}

// pack 4 floats -> 4 fp8 e4m3 (OCP, HW RNE+satfinite) in one uint32
__device__ __forceinline__ uint32_t pk_fp8x4(float4 v) {
    uint32_t w = 0;
    w = __builtin_amdgcn_cvt_pk_fp8_f32(v.x, v.y, w, false);  // bytes 0,1
    w = __builtin_amdgcn_cvt_pk_fp8_f32(v.z, v.w, w, true);   // bytes 2,3
    return w;
}

// ------- kernel 0: fp32 -> fp8 (+ pad) + ncap + per-image f16 Gram, one launch ----
// grid (NB, 15): y<14 -> convert 8 rows each; y==14 -> Gram block (reads fp32 im).
__global__ __launch_bounds__(256) void prep_kernel(
    const float* __restrict__ im, const float* __restrict__ s,
    uint8_t* __restrict__ im8, uint8_t* __restrict__ s8, float* __restrict__ ncap,
    f16* __restrict__ Mg16) {
    __shared__ __align__(16) char Gs[8192];   // gram staging [64 rows][128 B]
    const int b = blockIdx.x, y = blockIdx.y, t = threadIdx.x;

    if (y < 14) {
        const int lr = t >> 5, g = t & 31;   // local row 0..7, lane-in-row 0..31
        const int row = y * 8 + lr;          // 0..111
        if (row < MT) {
            uint32_t* dst = (uint32_t*)(im8 + ((size_t)b * MT + row) * ND);
            if (row < NR) {
                const float4* src = (const float4*)(im + ((size_t)b * NR + row) * ND);
                #pragma unroll
                for (int e = 0; e < 8; ++e)
                    dst[g + e * 32] = pk_fp8x4(src[g + e * 32]);
            } else {
                #pragma unroll
                for (int e = 0; e < 8; ++e) dst[g + e * 32] = 0u;
            }
        } else {
            const int w = row - MT;
            const float4* src = (const float4*)(s + ((size_t)b * NW + w) * ND);
            uint32_t* dst = (uint32_t*)(s8 + ((size_t)b * NW + w) * ND);
            float ss = 0.f;
            #pragma unroll
            for (int e = 0; e < 8; ++e) {
                float4 v = src[g + e * 32];
                dst[g + e * 32] = pk_fp8x4(v);
                ss += v.x * v.x + v.y * v.y + v.z * v.z + v.w * v.w;
            }
            #pragma unroll
            for (int off = 1; off < 32; off <<= 1) ss += __shfl_xor(ss, off, 32);
            if (g == 0) ncap[b * NW + w] = sqrtf(ss);
        }
        return;
    }

    // ---- Gram block: Mg16[b] = G . G^T, G = f16(im[b]) zero-padded to 64 rows ----
    const int wave = t >> 6, lane = t & 63;
    const int quad = lane >> 4, l16 = lane & 15;
    const int nt = wave;                     // n-tile 0..3 (cols); cols >=36 end up 0
    f32x4 acc[3];
    acc[0] = (f32x4){0.f, 0.f, 0.f, 0.f};
    acc[1] = (f32x4){0.f, 0.f, 0.f, 0.f};
    acc[2] = (f32x4){0.f, 0.f, 0.f, 0.f};
    const float* imb = im + (size_t)b * NR * ND;

    for (int kk = 0; kk < ND; kk += 64) {
        for (int cidx = t; cidx < 512; cidx += 256) {
            int row = cidx >> 3, c = cidx & 7;
            f16x8 hv;
            if (row < NR) {
                const float4* sp = (const float4*)(imb + (size_t)row * ND + kk + c * 8);
                float4 v0 = sp[0], v1 = sp[1];
                hv = (f16x8){(f16)v0.x, (f16)v0.y, (f16)v0.z, (f16)v0.w,
                             (f16)v1.x, (f16)v1.y, (f16)v1.z, (f16)v1.w};
            } else {
                hv = (f16x8){(f16)0.f, (f16)0.f, (f16)0.f, (f16)0.f,
                             (f16)0.f, (f16)0.f, (f16)0.f, (f16)0.f};
            }
            *(f16x8*)(Gs + row * 128 + ((c ^ (row & 7)) * 16)) = hv;
        }
        __syncthreads();
        #pragma unroll
        for (int ks = 0; ks < 2; ++ks) {
            int brow = nt * 16 + l16;
            f16x8 bf = *(const f16x8*)(Gs + brow * 128 + (((ks * 4 + quad) ^ (brow & 7)) * 16));
            #pragma unroll
            for (int mt = 0; mt < 3; ++mt) {
                int arow = mt * 16 + l16;
                f16x8 af = *(const f16x8*)(Gs + arow * 128 + (((ks * 4 + quad) ^ (arow & 7)) * 16));
                acc[mt] = __builtin_amdgcn_mfma_f32_16x16x32_f16(af, bf, acc[mt], 0, 0, 0);
            }
        }
        __syncthreads();
    }
    f16* Mb = Mg16 + (size_t)b * (MT * NW);
    #pragma unroll
    for (int mt = 0; mt < 3; ++mt) {
        #pragma unroll
        for (int r = 0; r < 4; ++r) {
            int row = mt * 16 + quad * 4 + r;
            Mb[row * NW + nt * 16 + l16] = (f16)acc[mt][r];
        }
    }
}

// ---------------- kernel B: fused GEMM + epilogue, MX-scaled fp8 ---------------
// Block tile 96x128 = 2 images x 2 captions; wave = one pair (acc[3][4]).
// K-loop: mfma_scale_f32_16x16x128_f8f6f4 with UNIT scales (0x7F = 2^0) —
// bit-identical math to fp8_fp8 but ~2x rate and 1/4 the MFMA instructions.
// Fragments 32B/lane via two ds_read_b128 (the conflict-free pattern).
// Staging identical to R12: BK=128, rows 128 B, exact XOR swizzle, 28KB.
#define A_LDS 12288   // 96 rows x 128 B
__global__ __launch_bounds__(256) void fused_pair_kernel(
    const uint8_t* __restrict__ im8, const uint8_t* __restrict__ s8,
    const int* __restrict__ s_l, const f16* __restrict__ Mg16,
    const float* __restrict__ ncap, float* __restrict__ scores) {
    __shared__ __align__(16) char lds[32768];   // staging 28KB; eT overlay 32KB
    const int t = threadIdx.x;
    const int wave = t >> 6, lane = t & 63;
    const int quad = lane >> 4, l16 = lane & 15;
    const int wi = wave >> 1, wj = wave & 1;

    // gx fast: XCD (~lin%8) sees gx = x, x+8, ... -> B slice (16 captions) L2-hot;
    // gy slow: all XCDs sweep the same A window concurrently (L2/L3-hot).
    const int lin = blockIdx.x;            // 0..4095
    const int gx = lin & 63, gy = lin >> 6;
    const int i = gy * 2 + wi;             // this wave's image
    const int j = gx * 2 + wj;             // this wave's caption
    const int L = s_l[j];

    const uint8_t* Ab = im8 + (size_t)gy * 2 * (MT * ND);   // 96 contiguous rows
    const uint8_t* Bb = s8 + (size_t)gx * 2 * (NW * ND);    // 128 contiguous rows

    // staging: 7 issues of 16B/thread per k128 iter (A q=0..2, B q=3..6)
    int goff[7];
    bool gact[7];
    const uint8_t* gbase[7];
    #pragma unroll
    for (int q = 0; q < 7; ++q) {
        int f = q * 4096 + t * 16;
        if (f < A_LDS) {
            int row = f >> 7, c = (f >> 4) & 7;
            goff[q] = row * ND + (c ^ (row & 7)) * 16;
            gact[q] = (row % MT) < NR;     // pad rows stay zero
            gbase[q] = Ab;
        } else {
            int f2 = f - A_LDS;
            int row = f2 >> 7, c = (f2 >> 4) & 7;
            goff[q] = row * ND + (c ^ (row & 7)) * 16;
            gact[q] = true;
            gbase[q] = Bb;
        }
    }

    // pre-zero the 24 pad rows of As (never DMA'd)
    if (t < 192) {
        int r = (t < 96) ? (36 + (t >> 3)) : (84 + ((t - 96) >> 3));
        *(float4*)(lds + r * 128 + (t & 7) * 16) = make_float4(0.f, 0.f, 0.f, 0.f);
    }

    f32x4 acc[3][4];
    #pragma unroll
    for (int mi = 0; mi < 3; ++mi)
        #pragma unroll
        for (int nt = 0; nt < 4; ++nt)
            acc[mi][nt] = (f32x4){0.f, 0.f, 0.f, 0.f};

    // this lane's k-range within the 128-B row: global chunks 2q, 2q+1
    const int c0 = quad * 2, c1 = quad * 2 + 1;

    for (int kk = 0; kk < ND; kk += 128) {
        #pragma unroll
        for (int q = 0; q < 7; ++q)
            if (gact[q]) gld_lds16(gbase[q] + goff[q] + kk, lds + q * 4096 + t * 16);
        __syncthreads();
        // B fragments first (32 regs), then one A fragment at a time (8 regs)
        i32x8 bf[4];
        #pragma unroll
        for (int nt = 0; nt < 4; ++nt) {
            int row = wj * 64 + nt * 16 + l16;
            const char* base = lds + A_LDS + row * 128;
            i32x4 lo = *(const i32x4*)(base + ((c0 ^ (row & 7)) * 16));
            i32x4 hi = *(const i32x4*)(base + ((c1 ^ (row & 7)) * 16));
            bf[nt] = (i32x8){lo.x, lo.y, lo.z, lo.w, hi.x, hi.y, hi.z, hi.w};
        }
        #pragma unroll
        for (int mi = 0; mi < 3; ++mi) {
            int row = wi * 48 + mi * 16 + l16;
            const char* base = lds + row * 128;
            i32x4 lo = *(const i32x4*)(base + ((c0 ^ (row & 7)) * 16));
            i32x4 hi = *(const i32x4*)(base + ((c1 ^ (row & 7)) * 16));
            i32x8 af = (i32x8){lo.x, lo.y, lo.z, lo.w, hi.x, hi.y, hi.z, hi.w};
            #pragma unroll
            for (int nt = 0; nt < 4; ++nt)
                acc[mi][nt] = __builtin_amdgcn_mfma_scale_f32_16x16x128_f8f6f4(
                    af, bf[nt], acc[mi][nt], 0, 0, 0, 0x7F, 0, 0x7F);
        }
        __syncthreads();
    }

    // ---- wave-private epilogue (verified R3..R12 math; C-layout shape-invariant) --
    char* waveE = lds + wave * 8192;   // staging LDS dead after final barrier
    {   // zero E^T rows 48..63 (chunks 6,7): pad/poison guard for quadform
        int col = lane;
        f16x8 z = {(f16)0.f,(f16)0.f,(f16)0.f,(f16)0.f,(f16)0.f,(f16)0.f,(f16)0.f,(f16)0.f};
        *(f16x8*)(waveE + col * 128 + ((6 ^ (col & 7)) * 16)) = z;
        *(f16x8*)(waveE + col * 128 + ((7 ^ (col & 7)) * 16)) = z;
    }

    // -- per-row l2-norm reciprocal (rows >= 36 -> 0) --
    float rn[3][4];
    #pragma unroll
    for (int mi = 0; mi < 3; ++mi) {
        #pragma unroll
        for (int r = 0; r < 4; ++r) {
            int row = mi * 16 + quad * 4 + r;
            float ss = 0.f;
            #pragma unroll
            for (int nt = 0; nt < 4; ++nt) {
                int col = nt * 16 + l16;
                float v = acc[mi][nt][r];
                float lv = v > 0.f ? v : 0.1f * v;
                if (col < L) ss += lv * lv;
            }
            ss += __shfl_xor(ss, 1, 64);
            ss += __shfl_xor(ss, 2, 64);
            ss += __shfl_xor(ss, 4, 64);
            ss += __shfl_xor(ss, 8, 64);
            rn[mi][r] = (row < NR) ? 1.0f / (sqrtf(ss) + EPSF) : 0.f;
        }
    }
    // -- e = exp(9*an): write E^T f16 (swizzled); cs/nu per-col partials --
    float cs[4] = {0.f, 0.f, 0.f, 0.f}, nu[4] = {0.f, 0.f, 0.f, 0.f};
    #pragma unroll
    for (int mi = 0; mi < 3; ++mi) {
        #pragma unroll
        for (int nt = 0; nt < 4; ++nt) {
            int col = nt * 16 + l16;
            f16x4 ew;
            #pragma unroll
            for (int r = 0; r < 4; ++r) {
                float v = acc[mi][nt][r];
                float lv = v > 0.f ? v : 0.1f * v;
                float e = __expf(LAM_SM * ((col < L) ? lv * rn[mi][r] : 0.f));
                ew[r] = (f16)e;
                if (mi * 16 + quad * 4 + r < NR) { cs[nt] += e; nu[nt] += e * v; }
            }
            int c = mi * 2 + (quad >> 1);
            *(f16x4*)(waveE + col * 128 + ((c ^ (col & 7)) * 16) + (quad & 1) * 8) = ew;
        }
    }
    #pragma unroll
    for (int nt = 0; nt < 4; ++nt) {
        cs[nt] += __shfl_xor(cs[nt], 16, 64); cs[nt] += __shfl_xor(cs[nt], 32, 64);
        nu[nt] += __shfl_xor(nu[nt], 16, 64); nu[nt] += __shfl_xor(nu[nt], 32, 64);
    }
    // acc dead here -> pressure drops before quadform.

    // -- quadform mi-at-a-time: y = M[mi,:] x E^T; qf += e . y --
    const f16* Mi = Mg16 + (size_t)i * (MT * NW);
    float qf[4] = {0.f, 0.f, 0.f, 0.f};
    #pragma unroll
    for (int mi = 0; mi < 3; ++mi) {
        f32x4 y[4];
        #pragma unroll
        for (int nt = 0; nt < 4; ++nt) y[nt] = (f32x4){0.f, 0.f, 0.f, 0.f};
        #pragma unroll
        for (int ks = 0; ks < 2; ++ks) {
            f16x8 aq = *(const f16x8*)(Mi + (mi * 16 + l16) * NW + ks * 32 + quad * 8);
            #pragma unroll
            for (int nt = 0; nt < 4; ++nt) {
                int col = nt * 16 + l16;
                int pch = (ks * 4 + quad) ^ (col & 7);
                f16x8 bq = *(const f16x8*)(waveE + col * 128 + pch * 16);
                y[nt] = __builtin_amdgcn_mfma_f32_16x16x32_f16(aq, bq, y[nt], 0, 0, 0);
            }
        }
        int row0 = mi * 16 + quad * 4;
        int c = row0 >> 3, sub = (row0 >> 2) & 1;
        #pragma unroll
        for (int nt = 0; nt < 4; ++nt) {
            int col = nt * 16 + l16;
            f16x4 ev = *(const f16x4*)(waveE + col * 128 + ((c ^ (col & 7)) * 16) + sub * 8);
            #pragma unroll
            for (int r = 0; r < 4; ++r) qf[nt] += y[nt][r] * (float)ev[r];
        }
    }
    #pragma unroll
    for (int nt = 0; nt < 4; ++nt) {
        qf[nt] += __shfl_xor(qf[nt], 16, 64); qf[nt] += __shfl_xor(qf[nt], 32, 64);
    }
    // -- finalize: cosine row values, LSE over words, write score --
    float lse = 0.f;
    #pragma unroll
    for (int nt = 0; nt < 4; ++nt) {
        int col = nt * 16 + l16;
        float num  = nu[nt] / cs[nt];
        float nwei = sqrtf(fmaxf(qf[nt], 0.f)) / cs[nt];
        float nc   = ncap[j * NW + col];
        float rowv = num / fmaxf(nc * nwei, EPSF);
        lse += (col < L) ? __expf(LAM_LSE * rowv) : 0.f;
    }
    lse += __shfl_xor(lse, 1, 64);
    lse += __shfl_xor(lse, 2, 64);
    lse += __shfl_xor(lse, 4, 64);
    lse += __shfl_xor(lse, 8, 64);
    if (lane == 0) scores[i * NB + j] = __logf(lse) / LAM_LSE;
}

// ---------------- kernel C: contrastive loss reduction (LDS-staged S) ------------
__global__ __launch_bounds__(256) void loss_kernel(const float* __restrict__ S,
                                                   float* __restrict__ out) {
    __shared__ __align__(16) float Sl[NB * NB];
    __shared__ float part[NB];
    __shared__ float wsum[2];
    int t = threadIdx.x;
    for (int c = t; c < (NB * NB) / 4; c += 256)
        ((float4*)Sl)[c] = ((const float4*)S)[c];
    __syncthreads();
    if (t < NB) {
        float dii = Sl[t * NB + t];
        float rmax = 0.f, cmax = 0.f;
        for (int k = 0; k < NB; ++k) {
            if (k != t) {
                float vs = MARGINF + Sl[t * NB + k] - dii;
                rmax = fmaxf(rmax, fmaxf(vs, 0.f));
                float vi = MARGINF + Sl[k * NB + t] - dii;
                cmax = fmaxf(cmax, fmaxf(vi, 0.f));
            }
        }
        part[t] = rmax + cmax;
    }
    __syncthreads();
    if (t < NB) {
        float v = part[t];
        #pragma unroll
        for (int off = 1; off < 64; off <<= 1) v += __shfl_xor(v, off, 64);
        if ((t & 63) == 0) wsum[t >> 6] = v;
    }
    __syncthreads();
    if (t == 0) out[0] = wsum[0] + wsum[1];
}

extern "C" void kernel_launch(void* const* d_in, const int* in_sizes, int n_in,
                              void* d_out, int out_size, void* d_ws, size_t ws_size,
                              hipStream_t stream) {
    const float* im  = (const float*)d_in[0];
    const float* s   = (const float*)d_in[1];
    const int*   s_l = (const int*)d_in[2];

    float*   scores = (float*)d_ws;                        // 16384 f32
    float*   ncap   = scores + NB * NB;                    // 8192 f32
    f16*     Mg16   = (f16*)(ncap + NB * NW);              // 128*48*64 f16
    uint8_t* im8    = (uint8_t*)(Mg16 + (size_t)NB * MT * NW);  // 128*48*1024 fp8
    uint8_t* s8     = im8 + (size_t)NB * MT * ND;          // 128*64*1024 fp8

    dim3 pgrid(NB, 15);
    prep_kernel<<<pgrid, 256, 0, stream>>>(im, s, im8, s8, ncap, Mg16);
    fused_pair_kernel<<<4096, 256, 0, stream>>>(im8, s8, s_l, Mg16, ncap, scores);
    loss_kernel<<<1, 256, 0, stream>>>(scores, (float*)d_out);
}